// Round 10
// baseline (297.150 us; speedup 1.0000x reference)
//
#include <hip/hip_runtime.h>
#include <hip/hip_bf16.h>
#include <hip/hip_fp16.h>

#define N_NODES 50000
#define N_EDGES 500000
#define F_DIM   128
#define N_REL   8
#define N_LAYERS 2
#define NEG_SLOPE 0.2f

#define NBLK_N ((N_NODES + 255) / 256)   // 196 blocks over nodes

typedef _Float16 half8 __attribute__((ext_vector_type(8)));
typedef float f32x4  __attribute__((ext_vector_type(4)));

// ---------------- helpers ----------------

__device__ inline float lrelu(float l) { return (l > 0.f) ? l : NEG_SLOPE * l; }

// ---------------- H prep: fp32 [N,128] -> fp16 (row-major) ------------------
__global__ __launch_bounds__(256) void prep_h(const float* __restrict__ H,
                                              _Float16* __restrict__ Hf) {
    const size_t i8 = (size_t)blockIdx.x * 256 + threadIdx.x;   // 8-elem group
    if (i8 >= (size_t)N_NODES * F_DIM / 8) return;
    const float* src = H + i8 * 8;
    float av[8];
    *(float4*)(av)     = *(const float4*)(src);
    *(float4*)(av + 4) = *(const float4*)(src + 4);
    alignas(16) _Float16 hb[8];
#pragma unroll
    for (int j = 0; j < 8; ++j) hb[j] = (_Float16)av[j];
    *(uint4*)(Hf + i8 * 8) = *(const uint4*)hb;
}

// ---------------- W prep: W[l,r,f,g] fp32 -> Wf[l,r,g,f] fp16 ---------------
__global__ __launch_bounds__(256) void prep_w(const float* __restrict__ W,
                                              _Float16* __restrict__ Wf) {
    __shared__ float tile[64][F_DIM + 1];
    const int mat = blockIdx.x;                      // l*N_REL + r
    const float* src = W + (size_t)mat * F_DIM * F_DIM;
    const int t = threadIdx.x;
    for (int hf = 0; hf < 2; ++hf) {
#pragma unroll
        for (int i = 0; i < 8; ++i) {
            int idx = t + i * 256;
            int f = idx >> 5, c4 = idx & 31;
            float4 v = *(const float4*)(src + (size_t)(hf * 64 + f) * F_DIM + c4 * 4);
            *(float4*)&tile[f][c4 * 4] = v;
        }
        __syncthreads();
        int g = t >> 1, fs = (t & 1) * 32;
        for (int c = 0; c < 4; ++c) {
            alignas(16) _Float16 th[8];
#pragma unroll
            for (int j = 0; j < 8; ++j) th[j] = (_Float16)tile[fs + c * 8 + j][g];
            size_t o = ((size_t)mat * F_DIM + g) * F_DIM + hf * 64 + fs + c * 8;
            *(uint4*)(Wf + o) = *(const uint4*)th;
        }
        __syncthreads();
    }
}

// ---------------- A-stationary fp16 MFMA GEMM, staged W, 4 tiles/block ------
// grid (98, 8), 256 threads (4 waves), ONE relation per block. Stage 32KB W[r]
// into XOR-swizzled LDS ONCE, single barrier, then 4 sequential 128-row tiles:
// {load A regs, 64 MFMA/wave, epilogue stores}. No barrier between tiles (LDS
// is read-only after stage), so tile-t stores drain under tile-t+1 compute.
// q/k dots inline (round-8: splitting them into extra serial dispatches loses).
// xw stored COLUMN-PERMUTED: xw'[row][ln*8+t] = C[row][t*16+ln].
// a_q/a_k stored [rel][node] (coalesced epilogue writes).
#define GBM 512
__global__ __launch_bounds__(256, 2) void gemm_xw(const _Float16* __restrict__ Hf,
                                                  const _Float16* __restrict__ Wf,
                                                  const float* __restrict__ qv_g,
                                                  const float* __restrict__ kv_g,
                                                  __half* __restrict__ xw,
                                                  float* __restrict__ a_q,
                                                  float* __restrict__ a_k) {
    __shared__ _Float16 lds[F_DIM * F_DIM];    // 32 KB, [col][f] XOR-swizzled
    const int r   = blockIdx.y;
    const int tid = threadIdx.x;
    const int lane = tid & 63, w = tid >> 6;
    const int q = lane >> 4, ln = lane & 15;

    // stage W[r] fp16: 2048 16B chunks, 8 per thread, XOR-swizzled
    {
        const _Float16* src = Wf + (size_t)r * F_DIM * F_DIM;
#pragma unroll
        for (int i = 0; i < 8; ++i) {
            int chunk = tid + i * 256;               // [0, 2048)
            int gg = chunk >> 4, c8 = chunk & 15;
            uint4 v = *(const uint4*)(src + gg * F_DIM + c8 * 8);
            *(uint4*)(lds + gg * F_DIM + ((c8 ^ (gg & 15)) * 8)) = v;
        }
    }

    float qvl[8], kvl[8];
#pragma unroll
    for (int t = 0; t < 8; ++t) {
        qvl[t] = qv_g[t * 16 + ln];
        kvl[t] = kv_g[t * 16 + ln];
    }

    __syncthreads();   // W staged; only barrier in the kernel

    for (int t4 = 0; t4 < 4; ++t4) {
        const int rb0 = blockIdx.x * GBM + t4 * 128;
        if (rb0 >= N_NODES) break;

        // pinned fp16 A for this lane's two row-tiles
        half8 Af[2][4];
#pragma unroll
        for (int rt = 0; rt < 2; ++rt) {
            int row = rb0 + w * 32 + rt * 16 + ln;
            int ar = (row < N_NODES) ? row : (N_NODES - 1);
            const _Float16* hp = Hf + (size_t)ar * F_DIM;
#pragma unroll
            for (int ks = 0; ks < 4; ++ks)
                Af[rt][ks] = *(const half8*)(hp + ks * 32 + q * 8);
        }

        f32x4 acc[2][8];
#pragma unroll
        for (int rt = 0; rt < 2; ++rt)
#pragma unroll
            for (int t = 0; t < 8; ++t) acc[rt][t] = (f32x4)(0.f);

#pragma unroll
        for (int ks = 0; ks < 4; ++ks) {
            const int jx = (((ks * 4 + q) ^ ln)) << 3;   // swizzled 16B chunk
            half8 Bf[8];
#pragma unroll
            for (int c = 0; c < 8; ++c)
                Bf[c] = *(const half8*)(lds + (c * 16 + ln) * F_DIM + jx);
            // 16 independent accumulator chains; each B feeds 2 MFMAs
#pragma unroll
            for (int c = 0; c < 8; ++c)
#pragma unroll
                for (int rt = 0; rt < 2; ++rt)
                    acc[rt][c] = __builtin_amdgcn_mfma_f32_16x16x32_f16(Af[rt][ks], Bf[c], acc[rt][c], 0, 0, 0);
        }

        // epilogue: permuted 16B stores + in-wave q/k dots (no atomics)
#pragma unroll
        for (int rt = 0; rt < 2; ++rt) {
            float pq[4], pk[4];
#pragma unroll
            for (int reg = 0; reg < 4; ++reg) {
                const int row = rb0 + w * 32 + rt * 16 + q * 4 + reg;
                alignas(16) unsigned short hs[8];
                float sq = 0.f, sk = 0.f;
#pragma unroll
                for (int t = 0; t < 8; ++t) {
                    float v = acc[rt][t][reg];
                    __half hv = __float2half(v);
                    hs[t] = *reinterpret_cast<unsigned short*>(&hv);
                    sq = fmaf(v, qvl[t], sq);
                    sk = fmaf(v, kvl[t], sk);
                }
                if (row < N_NODES)
                    *(uint4*)(xw + ((size_t)r * N_NODES + row) * F_DIM + ln * 8) = *(const uint4*)hs;
                pq[reg] = sq; pk[reg] = sk;
            }
#pragma unroll
            for (int reg = 0; reg < 4; ++reg) {
#pragma unroll
                for (int m = 1; m <= 8; m <<= 1) {
                    pq[reg] += __shfl_xor(pq[reg], m);
                    pk[reg] += __shfl_xor(pk[reg], m);
                }
            }
            if (ln == 0) {
#pragma unroll
                for (int reg = 0; reg < 4; ++reg) {
                    const int row = rb0 + w * 32 + rt * 16 + q * 4 + reg;
                    if (row < N_NODES) {
                        a_q[r * N_NODES + row] = pq[reg];
                        a_k[r * N_NODES + row] = pk[reg];
                    }
                }
            }
        }
    }
}

// ---------------- CSR build (atomic segment allocation, no scans) ----------
// Segment ORDER in `sorted` is arbitrary (atomicAdd allocation): agg only
// needs per-node contiguity, which row_start[d] + cnt[d] provides.

__global__ __launch_bounds__(256) void count_kernel(const int* __restrict__ dstp,
                                                    int* __restrict__ cnt) {
    int e = blockIdx.x * 256 + threadIdx.x;
    if (e < N_EDGES) atomicAdd(cnt + dstp[e], 1);
}

__global__ __launch_bounds__(256) void alloc_kernel(const int* __restrict__ cnt,
                                                    int* __restrict__ gtotal,
                                                    int* __restrict__ row_start) {
    int d = blockIdx.x * 256 + threadIdx.x;
    if (d < N_NODES) row_start[d] = atomicAdd(gtotal, cnt[d]);
}

__global__ __launch_bounds__(256) void scatter_kernel(const int* __restrict__ srcp,
                                                      const int* __restrict__ dstp,
                                                      const int* __restrict__ etp,
                                                      const int* __restrict__ row_start,
                                                      int* __restrict__ cursor,
                                                      unsigned* __restrict__ sorted,
                                                      unsigned short* __restrict__ dst16) {
    int e = blockIdx.x * 256 + threadIdx.x;
    if (e >= N_EDGES) return;
    int d = dstp[e];
    int pos = atomicAdd(cursor + d, 1);
    int j = row_start[d] + pos;
    sorted[j] = (unsigned)srcp[e] | ((unsigned)etp[e] << 16);
    dst16[j] = (unsigned short)d;
}

// ---------------- edge-parallel logits -> {packed src|rel, exp(lgt)} --------
// Logits are bounded (~N(0,2.5), |l| << 80, validated rounds 8/9), so exp
// never overflows and softmax needs no max-subtract anywhere:
// alpha = ex / sum(ex) exactly. agg's hot path then needs ONE 8B load.
__global__ __launch_bounds__(256) void logits_kernel(const float* __restrict__ a_q,
                                                     const float* __restrict__ a_k,
                                                     const unsigned* __restrict__ sorted,
                                                     const unsigned short* __restrict__ dst16,
                                                     uint2* __restrict__ elgt) {
    int j = blockIdx.x * 256 + threadIdx.x;
    if (j >= N_EDGES) return;
    unsigned p = sorted[j];
    int s = p & 0xffff, t = p >> 16;
    int d = dst16[j];
    float ex = __expf(lrelu(a_q[t * N_NODES + d] + a_k[t * N_NODES + s]));
    elgt[j] = make_uint2(p, __float_as_uint(ex));
}

// ---------------- fused softmax + aggregate + bias + relu ----------------
// xw is column-permuted: position p holds col (p&7)*16 + (p>>3).
// Block = 16 dst nodes; wave owns 4 nodes in 16-lane quarters (deg<=16 covers
// ~97% of nodes at Poisson-10). Pre-gather chain: one coalesced uint2 load.
// Waves with any node deg>16 process their nodes sequentially full-wave;
// deg>64 scalar fallback. No max-subtract (see logits_kernel).
__device__ inline void accum8(float* acc, uint4 v, float a) {
    const __half2* h2 = reinterpret_cast<const __half2*>(&v);
#pragma unroll
    for (int t = 0; t < 4; ++t) {
        float2 f = __half22float2(h2[t]);
        acc[t * 2]     = fmaf(a, f.x, acc[t * 2]);
        acc[t * 2 + 1] = fmaf(a, f.y, acc[t * 2 + 1]);
    }
}
__device__ inline const uint4* xwrow(const __half* xw, unsigned p, int ln) {
    return (const uint4*)(xw + (((size_t)(p >> 16)) * N_NODES + (p & 0xffff)) * F_DIM + ln * 8);
}

__global__ __launch_bounds__(256) void agg_fused(const __half* __restrict__ xw,
                                                 const uint2* __restrict__ elgt,
                                                 const int* __restrict__ row_start,
                                                 const int* __restrict__ degp,
                                                 const float* __restrict__ bias,
                                                 float* __restrict__ outp,
                                                 _Float16* __restrict__ hfp) {
    const int lane = threadIdx.x & 63;
    const int wave = threadIdx.x >> 6;
    const int ql = lane & 15;
    const int d0 = blockIdx.x * 16 + wave * 4;
    if (d0 >= N_NODES) return;
    const int dmy = d0 + (lane >> 4);
    const int dv = (dmy < N_NODES) ? dmy : (N_NODES - 1);
    const int beg = row_start[dv];
    const int deg = (dmy < N_NODES) ? degp[dv] : 0;
    int cmax = deg;
    cmax = max(cmax, __shfl_xor(cmax, 16));
    cmax = max(cmax, __shfl_xor(cmax, 32));

    if (cmax <= 16) {
        // ---- quarter path: one node per 16-lane group ----
        unsigned p = 0;
        float ex = 0.f;
        if (ql < deg) {
            uint2 e = elgt[beg + ql];
            p = e.x;
            ex = __uint_as_float(e.y);
        }
        float acc[8] = {0, 0, 0, 0, 0, 0, 0, 0};
        // slot broadcast: all 16 lanes process edge i+s together (lane ql
        // takes col-slice ql); lanes >= deg carry p=0 (valid row), ex=0.
        for (int i = 0; i < deg; i += 4) {
            unsigned p0 = __shfl(p, i, 16);
            unsigned p1 = __shfl(p, i + 1, 16);
            unsigned p2 = __shfl(p, i + 2, 16);
            unsigned p3 = __shfl(p, i + 3, 16);
            float a0 = __shfl(ex, i, 16);
            float a1 = __shfl(ex, i + 1, 16);
            float a2 = __shfl(ex, i + 2, 16);
            float a3 = __shfl(ex, i + 3, 16);
            uint4 v0 = *xwrow(xw, p0, ql);
            uint4 v1 = *xwrow(xw, p1, ql);
            uint4 v2 = *xwrow(xw, p2, ql);
            uint4 v3 = *xwrow(xw, p3, ql);
            accum8(acc, v0, a0);
            accum8(acc, v1, a1);
            accum8(acc, v2, a2);
            accum8(acc, v3, a3);
        }
        float dsum = ex;
#pragma unroll
        for (int off = 8; off > 0; off >>= 1) dsum += __shfl_xor(dsum, off, 16);

        if (dmy < N_NODES) {
            const float inv = 1.f / (dsum + 1e-16f);
#pragma unroll
            for (int t = 0; t < 8; ++t) {
                const int col = t * 16 + ql;
                const float v = fmaxf(fmaf(acc[t], inv, bias[col]), 0.f);
                if (outp) outp[(size_t)dmy * F_DIM + col] = v;
                if (hfp)  hfp[(size_t)dmy * F_DIM + col] = (_Float16)v;
            }
        }
    } else {
        // ---- rare: process the wave's 4 nodes sequentially, full wave ----
        const int g = lane >> 4, ln = lane & 15;
        for (int h = 0; h < 4; ++h) {
            const int dd = d0 + h;
            if (dd >= N_NODES) continue;
            const int b = __shfl(beg, h * 16);
            const int c = __shfl(deg, h * 16);
            if (c <= 64) {
                unsigned p = 0;
                float ex = 0.f;
                if (lane < c) {
                    uint2 e = elgt[b + lane];
                    p = e.x;
                    ex = __uint_as_float(e.y);
                }
                float acc[8] = {0, 0, 0, 0, 0, 0, 0, 0};
                for (int i = 0; i < c; i += 8) {
                    unsigned p0 = __shfl(p, i + g);
                    unsigned p1 = __shfl(p, i + 4 + g);
                    float a0 = __shfl(ex, i + g);
                    float a1 = __shfl(ex, i + 4 + g);
                    uint4 v0 = *xwrow(xw, p0, ln);
                    uint4 v1 = *xwrow(xw, p1, ln);
                    accum8(acc, v0, a0);
                    accum8(acc, v1, a1);
                }
                float dsum = ex;
#pragma unroll
                for (int off = 32; off > 0; off >>= 1) dsum += __shfl_xor(dsum, off);
#pragma unroll
                for (int t = 0; t < 8; ++t) {
                    acc[t] += __shfl_xor(acc[t], 16);
                    acc[t] += __shfl_xor(acc[t], 32);
                }
                const float inv = 1.f / (dsum + 1e-16f);
#pragma unroll
                for (int j = 0; j < 2; ++j) {
                    const int t = g * 2 + j;
                    const int col = t * 16 + ln;
                    const float v = fmaxf(fmaf(acc[t], inv, bias[col]), 0.f);
                    if (outp) outp[(size_t)dd * F_DIM + col] = v;
                    if (hfp)  hfp[(size_t)dd * F_DIM + col] = (_Float16)v;
                }
            } else {
                // very-high-degree fallback: per-lane 2-col scalar path
                const int p0 = lane * 2;
                const int c0 = (p0 & 7) * 16 + (p0 >> 3);
                const int c1 = c0 + 16;
                float2 acc = make_float2(bias[c0], bias[c1]);
                float dsum = 0.f;
                for (int i = b + lane; i < b + c; i += 64)
                    dsum += __uint_as_float(elgt[i].y);
#pragma unroll
                for (int off = 32; off > 0; off >>= 1) dsum += __shfl_xor(dsum, off);
                const float inv = 1.f / (dsum + 1e-16f);
                float sx = 0.f, sy = 0.f;
                for (int i = b; i < b + c; ++i) {
                    uint2 e = elgt[i];
                    float alpha = __uint_as_float(e.y);
                    const __half2 h2 = *((const __half2*)xw + (((size_t)(e.x >> 16)) * N_NODES + (e.x & 0xffff)) * (F_DIM / 2) + lane);
                    float2 v = make_float2(__half2float(h2.x), __half2float(h2.y));
                    sx = fmaf(alpha, v.x, sx);
                    sy = fmaf(alpha, v.y, sy);
                }
                acc.x += sx * inv;
                acc.y += sy * inv;
                const float v0 = fmaxf(acc.x, 0.f), v1 = fmaxf(acc.y, 0.f);
                if (outp) { outp[(size_t)dd * F_DIM + c0] = v0; outp[(size_t)dd * F_DIM + c1] = v1; }
                if (hfp)  { hfp[(size_t)dd * F_DIM + c0] = (_Float16)v0; hfp[(size_t)dd * F_DIM + c1] = (_Float16)v1; }
            }
        }
    }
}

// ---------------- driver ----------------

extern "C" void kernel_launch(void* const* d_in, const int* in_sizes, int n_in,
                              void* d_out, int out_size, void* d_ws, size_t ws_size,
                              hipStream_t stream) {
    const float* x     = (const float*)d_in[0];
    const float* W     = (const float*)d_in[1];
    const float* att_q = (const float*)d_in[2];
    const float* att_k = (const float*)d_in[3];
    const float* bias  = (const float*)d_in[4];
    const int* ei      = (const int*)d_in[5];
    const int* etp     = (const int*)d_in[6];
    const int* srcp = ei;
    const int* dstp = ei + N_EDGES;
    float* out = (float*)d_out;
    char* ws   = (char*)d_ws;

    size_t off = 0;
    auto alloc = [&](size_t bytes) {
        void* p = ws + off;
        off = (off + bytes + 511) & ~(size_t)511;
        return p;
    };
    __half* xw       = (__half*)alloc((size_t)N_REL * N_NODES * F_DIM * sizeof(__half));
    float* a_q       = (float*)alloc((size_t)N_REL * N_NODES * sizeof(float));
    float* a_k       = (float*)alloc((size_t)N_REL * N_NODES * sizeof(float));
    int* cnt         = (int*)alloc(((size_t)2 * N_NODES + 256) * sizeof(int)); // cnt + cursor + gtotal
    int* cursor      = cnt + N_NODES;
    int* gtotal      = cnt + 2 * N_NODES;
    int* row_start   = (int*)alloc((size_t)N_NODES * sizeof(int));
    unsigned* sorted = (unsigned*)alloc((size_t)N_EDGES * sizeof(unsigned));
    unsigned short* dst16 = (unsigned short*)alloc((size_t)N_EDGES * sizeof(unsigned short));
    uint2* elgt      = (uint2*)alloc((size_t)N_EDGES * sizeof(uint2));
    _Float16* Wf     = (_Float16*)alloc((size_t)N_LAYERS * N_REL * F_DIM * F_DIM * sizeof(_Float16));
    _Float16* Hf     = (_Float16*)alloc((size_t)N_NODES * F_DIM * sizeof(_Float16));

    prep_w<<<N_LAYERS * N_REL, 256, 0, stream>>>(W, Wf);
    hipMemsetAsync(cnt, 0, ((size_t)2 * N_NODES + 256) * sizeof(int), stream);
    count_kernel<<<(N_EDGES + 255) / 256, 256, 0, stream>>>(dstp, cnt);
    alloc_kernel<<<NBLK_N, 256, 0, stream>>>(cnt, gtotal, row_start);
    scatter_kernel<<<(N_EDGES + 255) / 256, 256, 0, stream>>>(
        srcp, dstp, etp, row_start, cursor, sorted, dst16);

    const int grid_h = (N_NODES * F_DIM / 8 + 255) / 256;   // 3125
    const int grid_m = (N_NODES + GBM - 1) / GBM;           // 98
    const int grid_e = (N_EDGES + 255) / 256;               // 1954
    prep_h<<<grid_h, 256, 0, stream>>>(x, Hf);              // layer-0 input only
    for (int l = 0; l < N_LAYERS; ++l) {
        gemm_xw<<<dim3(grid_m, N_REL), 256, 0, stream>>>(
            Hf, Wf + (size_t)l * N_REL * F_DIM * F_DIM,
            att_q + l * F_DIM, att_k + l * F_DIM,
            xw, a_q, a_k);
        logits_kernel<<<grid_e, 256, 0, stream>>>(a_q, a_k, sorted, dst16, elgt);
        const bool last = (l == N_LAYERS - 1);
        agg_fused<<<(N_NODES + 15) / 16, 256, 0, stream>>>(
            xw, elgt, row_start, cnt, bias + l * F_DIM,
            last ? out : nullptr,
            last ? nullptr : Hf);
    }
}

// Round 11
// 279.368 us; speedup vs baseline: 1.0637x; 1.0637x over previous
//
#include <hip/hip_runtime.h>
#include <hip/hip_bf16.h>
#include <hip/hip_fp16.h>

#define N_NODES 50000
#define N_EDGES 500000
#define F_DIM   128
#define N_REL   8
#define N_LAYERS 2
#define NEG_SLOPE 0.2f

#define NBLK_N ((N_NODES + 255) / 256)   // 196 blocks over nodes

typedef _Float16 half8 __attribute__((ext_vector_type(8)));
typedef float f32x4  __attribute__((ext_vector_type(4)));

// ---------------- helpers ----------------

__device__ inline float lrelu(float l) { return (l > 0.f) ? l : NEG_SLOPE * l; }

// ---------------- H prep: fp32 [N,128] -> fp16 (row-major) ------------------
__global__ __launch_bounds__(256) void prep_h(const float* __restrict__ H,
                                              _Float16* __restrict__ Hf) {
    const size_t i8 = (size_t)blockIdx.x * 256 + threadIdx.x;   // 8-elem group
    if (i8 >= (size_t)N_NODES * F_DIM / 8) return;
    const float* src = H + i8 * 8;
    float av[8];
    *(float4*)(av)     = *(const float4*)(src);
    *(float4*)(av + 4) = *(const float4*)(src + 4);
    alignas(16) _Float16 hb[8];
#pragma unroll
    for (int j = 0; j < 8; ++j) hb[j] = (_Float16)av[j];
    *(uint4*)(Hf + i8 * 8) = *(const uint4*)hb;
}

// ---------------- W prep: W[l,r,f,g] fp32 -> Wf[l,r,g,f] fp16 ---------------
__global__ __launch_bounds__(256) void prep_w(const float* __restrict__ W,
                                              _Float16* __restrict__ Wf) {
    __shared__ float tile[64][F_DIM + 1];
    const int mat = blockIdx.x;                      // l*N_REL + r
    const float* src = W + (size_t)mat * F_DIM * F_DIM;
    const int t = threadIdx.x;
    for (int hf = 0; hf < 2; ++hf) {
#pragma unroll
        for (int i = 0; i < 8; ++i) {
            int idx = t + i * 256;
            int f = idx >> 5, c4 = idx & 31;
            float4 v = *(const float4*)(src + (size_t)(hf * 64 + f) * F_DIM + c4 * 4);
            *(float4*)&tile[f][c4 * 4] = v;
        }
        __syncthreads();
        int g = t >> 1, fs = (t & 1) * 32;
        for (int c = 0; c < 4; ++c) {
            alignas(16) _Float16 th[8];
#pragma unroll
            for (int j = 0; j < 8; ++j) th[j] = (_Float16)tile[fs + c * 8 + j][g];
            size_t o = ((size_t)mat * F_DIM + g) * F_DIM + hf * 64 + fs + c * 8;
            *(uint4*)(Wf + o) = *(const uint4*)th;
        }
        __syncthreads();
    }
}

// ---------------- A-stationary fp16 MFMA GEMM, staged W, 2 tiles/block ------
// grid (196, 8), 256 threads (4 waves), ONE relation per block. Stage 32KB
// W[r] into XOR-swizzled LDS once, single barrier, then 2 sequential 128-row
// tiles. GBM=256 (was 512): 1568 blocks = 6.125/CU vs 784 = 3.06/CU — the
// 3-vs-4-blocks/CU quantization tail (33% of dispatch time) drops to ~1/6 of
// a half-length block. Extra W re-staging is L2-resident (256 KB/layer total).
// q/k dots inline (round-8: separate dispatches lose to launch latency).
// xw stored COLUMN-PERMUTED: xw'[row][ln*8+t] = C[row][t*16+ln].
// a_q/a_k stored [rel][node] (coalesced epilogue writes).
#define GBM 256
__global__ __launch_bounds__(256, 2) void gemm_xw(const _Float16* __restrict__ Hf,
                                                  const _Float16* __restrict__ Wf,
                                                  const float* __restrict__ qv_g,
                                                  const float* __restrict__ kv_g,
                                                  __half* __restrict__ xw,
                                                  float* __restrict__ a_q,
                                                  float* __restrict__ a_k) {
    __shared__ _Float16 lds[F_DIM * F_DIM];    // 32 KB, [col][f] XOR-swizzled
    const int r   = blockIdx.y;
    const int tid = threadIdx.x;
    const int lane = tid & 63, w = tid >> 6;
    const int q = lane >> 4, ln = lane & 15;

    // stage W[r] fp16: 2048 16B chunks, 8 per thread, XOR-swizzled
    {
        const _Float16* src = Wf + (size_t)r * F_DIM * F_DIM;
#pragma unroll
        for (int i = 0; i < 8; ++i) {
            int chunk = tid + i * 256;               // [0, 2048)
            int gg = chunk >> 4, c8 = chunk & 15;
            uint4 v = *(const uint4*)(src + gg * F_DIM + c8 * 8);
            *(uint4*)(lds + gg * F_DIM + ((c8 ^ (gg & 15)) * 8)) = v;
        }
    }

    float qvl[8], kvl[8];
#pragma unroll
    for (int t = 0; t < 8; ++t) {
        qvl[t] = qv_g[t * 16 + ln];
        kvl[t] = kv_g[t * 16 + ln];
    }

    __syncthreads();   // W staged; only barrier in the kernel

    for (int t4 = 0; t4 < 2; ++t4) {
        const int rb0 = blockIdx.x * GBM + t4 * 128;
        if (rb0 >= N_NODES) break;

        // pinned fp16 A for this lane's two row-tiles
        half8 Af[2][4];
#pragma unroll
        for (int rt = 0; rt < 2; ++rt) {
            int row = rb0 + w * 32 + rt * 16 + ln;
            int ar = (row < N_NODES) ? row : (N_NODES - 1);
            const _Float16* hp = Hf + (size_t)ar * F_DIM;
#pragma unroll
            for (int ks = 0; ks < 4; ++ks)
                Af[rt][ks] = *(const half8*)(hp + ks * 32 + q * 8);
        }

        f32x4 acc[2][8];
#pragma unroll
        for (int rt = 0; rt < 2; ++rt)
#pragma unroll
            for (int t = 0; t < 8; ++t) acc[rt][t] = (f32x4)(0.f);

#pragma unroll
        for (int ks = 0; ks < 4; ++ks) {
            const int jx = (((ks * 4 + q) ^ ln)) << 3;   // swizzled 16B chunk
            half8 Bf[8];
#pragma unroll
            for (int c = 0; c < 8; ++c)
                Bf[c] = *(const half8*)(lds + (c * 16 + ln) * F_DIM + jx);
            // 16 independent accumulator chains; each B feeds 2 MFMAs
#pragma unroll
            for (int c = 0; c < 8; ++c)
#pragma unroll
                for (int rt = 0; rt < 2; ++rt)
                    acc[rt][c] = __builtin_amdgcn_mfma_f32_16x16x32_f16(Af[rt][ks], Bf[c], acc[rt][c], 0, 0, 0);
        }

        // epilogue: permuted 16B stores + in-wave q/k dots (no atomics)
#pragma unroll
        for (int rt = 0; rt < 2; ++rt) {
            float pq[4], pk[4];
#pragma unroll
            for (int reg = 0; reg < 4; ++reg) {
                const int row = rb0 + w * 32 + rt * 16 + q * 4 + reg;
                alignas(16) unsigned short hs[8];
                float sq = 0.f, sk = 0.f;
#pragma unroll
                for (int t = 0; t < 8; ++t) {
                    float v = acc[rt][t][reg];
                    __half hv = __float2half(v);
                    hs[t] = *reinterpret_cast<unsigned short*>(&hv);
                    sq = fmaf(v, qvl[t], sq);
                    sk = fmaf(v, kvl[t], sk);
                }
                if (row < N_NODES)
                    *(uint4*)(xw + ((size_t)r * N_NODES + row) * F_DIM + ln * 8) = *(const uint4*)hs;
                pq[reg] = sq; pk[reg] = sk;
            }
#pragma unroll
            for (int reg = 0; reg < 4; ++reg) {
#pragma unroll
                for (int m = 1; m <= 8; m <<= 1) {
                    pq[reg] += __shfl_xor(pq[reg], m);
                    pk[reg] += __shfl_xor(pk[reg], m);
                }
            }
            if (ln == 0) {
#pragma unroll
                for (int reg = 0; reg < 4; ++reg) {
                    const int row = rb0 + w * 32 + rt * 16 + q * 4 + reg;
                    if (row < N_NODES) {
                        a_q[r * N_NODES + row] = pq[reg];
                        a_k[r * N_NODES + row] = pk[reg];
                    }
                }
            }
        }
    }
}

// ---------------- CSR build ----------------

__global__ __launch_bounds__(256) void count_kernel(const int* __restrict__ dstp,
                                                    int* __restrict__ cnt) {
    int e = blockIdx.x * 256 + threadIdx.x;
    if (e < N_EDGES) atomicAdd(cnt + dstp[e], 1);
}

__global__ __launch_bounds__(256) void block_sum_kernel(const int* __restrict__ cnt,
                                                        int* __restrict__ partial) {
    __shared__ int s[256];
    int idx = blockIdx.x * 256 + threadIdx.x;
    int v = (idx < N_NODES) ? cnt[idx] : 0;
    s[threadIdx.x] = v;
    __syncthreads();
    for (int off = 128; off > 0; off >>= 1) {
        if (threadIdx.x < off) s[threadIdx.x] += s[threadIdx.x + off];
        __syncthreads();
    }
    if (threadIdx.x == 0) partial[blockIdx.x] = s[0];
}

__global__ __launch_bounds__(256) void scan_partials_kernel(int* __restrict__ partial,
                                                            int* __restrict__ row_ptr) {
    __shared__ int s[256];
    int t = threadIdx.x;
    int v = (t < NBLK_N) ? partial[t] : 0;
    s[t] = v;
    __syncthreads();
#pragma unroll
    for (int off = 1; off < 256; off <<= 1) {
        int x = (t >= off) ? s[t - off] : 0;
        __syncthreads();
        s[t] += x;
        __syncthreads();
    }
    if (t < NBLK_N) partial[t] = s[t] - v;
    if (t == 0) row_ptr[N_NODES] = N_EDGES;
}

__global__ __launch_bounds__(256) void scan_block_kernel(const int* __restrict__ cnt,
                                                         const int* __restrict__ partial,
                                                         int* __restrict__ row_ptr) {
    __shared__ int s[256];
    int t = threadIdx.x;
    int idx = blockIdx.x * 256 + t;
    int v = (idx < N_NODES) ? cnt[idx] : 0;
    s[t] = v;
    __syncthreads();
#pragma unroll
    for (int off = 1; off < 256; off <<= 1) {
        int x = (t >= off) ? s[t - off] : 0;
        __syncthreads();
        s[t] += x;
        __syncthreads();
    }
    if (idx < N_NODES) row_ptr[idx] = partial[blockIdx.x] + s[t] - v;
}

__global__ __launch_bounds__(256) void scatter_kernel(const int* __restrict__ srcp,
                                                      const int* __restrict__ dstp,
                                                      const int* __restrict__ etp,
                                                      const int* __restrict__ row_ptr,
                                                      int* __restrict__ cursor,
                                                      unsigned* __restrict__ sorted,
                                                      unsigned short* __restrict__ dst16) {
    int e = blockIdx.x * 256 + threadIdx.x;
    if (e >= N_EDGES) return;
    int d = dstp[e];
    int pos = atomicAdd(cursor + d, 1);
    int j = row_ptr[d] + pos;
    sorted[j] = (unsigned)srcp[e] | ((unsigned)etp[e] << 16);
    dst16[j] = (unsigned short)d;
}

// ---------------- edge-parallel logits --------------------------------------
__global__ __launch_bounds__(256) void logits_kernel(const float* __restrict__ a_q,
                                                     const float* __restrict__ a_k,
                                                     const unsigned* __restrict__ sorted,
                                                     const unsigned short* __restrict__ dst16,
                                                     float* __restrict__ lgt) {
    int j = blockIdx.x * 256 + threadIdx.x;
    if (j >= N_EDGES) return;
    unsigned p = sorted[j];
    int s = p & 0xffff, t = p >> 16;
    int d = dst16[j];
    lgt[j] = lrelu(a_q[t * N_NODES + d] + a_k[t * N_NODES + s]);
}

// ---------------- fused softmax + aggregate + bias + relu ----------------
// xw is column-permuted: position p holds col (p&7)*16 + (p>>3).
// Block = 8 dst nodes; wave owns 2 nodes in 32-lane halves (deg<=32 covers
// ~all nodes at avg degree 10). Hot path skips the max-subtract: logits are
// ~N(0,2.5) (|l| << 80), so exp(l) is safe in fp32 and alpha is identical
// after the deferred divide. 8 edges/iter (4 loads in flight per half).
__device__ inline void accum8(float* acc, uint4 v, float a) {
    const __half2* h2 = reinterpret_cast<const __half2*>(&v);
#pragma unroll
    for (int t = 0; t < 4; ++t) {
        float2 f = __half22float2(h2[t]);
        acc[t * 2]     = fmaf(a, f.x, acc[t * 2]);
        acc[t * 2 + 1] = fmaf(a, f.y, acc[t * 2 + 1]);
    }
}
__device__ inline const uint4* xwrow(const __half* xw, unsigned p, int ln) {
    return (const uint4*)(xw + (((size_t)(p >> 16)) * N_NODES + (p & 0xffff)) * F_DIM + ln * 8);
}

__global__ __launch_bounds__(256) void agg_fused(const __half* __restrict__ xw,
                                                 const float* __restrict__ lgt,
                                                 const int* __restrict__ row_ptr,
                                                 const unsigned* __restrict__ sorted,
                                                 const float* __restrict__ bias,
                                                 float* __restrict__ outp,
                                                 _Float16* __restrict__ hfp) {
    const int lane = threadIdx.x & 63;
    const int wave = threadIdx.x >> 6;
    const int half = lane >> 5, hl = lane & 31;
    const int d0 = blockIdx.x * 8 + wave * 2;
    if (d0 >= N_NODES) return;
    const int dmy = d0 + half;
    const int dv = (dmy < N_NODES) ? dmy : (N_NODES - 1);
    const int beg = row_ptr[dv], end = row_ptr[dv + 1];
    int cnt = (dmy < N_NODES) ? (end - beg) : 0;
    const int cntO = __shfl_xor(cnt, 32);
    const int cmax = (cnt > cntO) ? cnt : cntO;

    if (cmax <= 32) {
        // ---- half-wave path: one node per 32-lane half, no max-subtract ----
        unsigned p = 0;
        float ex = 0.f;
        if (hl < cnt) {
            p = sorted[beg + hl];
            ex = __expf(lgt[beg + hl]);
        }

        const int gg = hl >> 4, ln = hl & 15;
        float acc[8] = {0, 0, 0, 0, 0, 0, 0, 0};
        // 8 edges/iter; max shfl index 31 (cnt<=32); lanes>=cnt carry ex=0.
        for (int i = 0; i < cnt; i += 8) {
            unsigned p0 = __shfl(p, i + gg, 32);
            unsigned p1 = __shfl(p, i + 2 + gg, 32);
            unsigned p2 = __shfl(p, i + 4 + gg, 32);
            unsigned p3 = __shfl(p, i + 6 + gg, 32);
            float a0 = __shfl(ex, i + gg, 32);
            float a1 = __shfl(ex, i + 2 + gg, 32);
            float a2 = __shfl(ex, i + 4 + gg, 32);
            float a3 = __shfl(ex, i + 6 + gg, 32);
            uint4 v0 = *xwrow(xw, p0, ln);
            uint4 v1 = *xwrow(xw, p1, ln);
            uint4 v2 = *xwrow(xw, p2, ln);
            uint4 v3 = *xwrow(xw, p3, ln);
            accum8(acc, v0, a0);
            accum8(acc, v1, a1);
            accum8(acc, v2, a2);
            accum8(acc, v3, a3);
        }
        float dsum = ex;
#pragma unroll
        for (int off = 16; off > 0; off >>= 1) dsum += __shfl_xor(dsum, off, 32);
#pragma unroll
        for (int t = 0; t < 8; ++t) acc[t] += __shfl_xor(acc[t], 16, 32);

        if (dmy < N_NODES) {
            const float inv = 1.f / (dsum + 1e-16f);
#pragma unroll
            for (int j = 0; j < 4; ++j) {
                const int t = gg * 4 + j;
                const int col = t * 16 + ln;
                const float v = fmaxf(fmaf(acc[t], inv, bias[col]), 0.f);
                if (outp) outp[(size_t)dmy * F_DIM + col] = v;
                if (hfp)  hfp[(size_t)dmy * F_DIM + col] = (_Float16)v;
            }
        }
    } else {
        // ---- rare: process each node with the full wave sequentially ----
        const int g = lane >> 4, ln = lane & 15;
        for (int h = 0; h < 2; ++h) {
            const int dd = d0 + h;
            if (dd >= N_NODES) continue;
            const int b = __shfl(beg, h * 32);
            const int c = __shfl(cnt, h * 32);
            if (c <= 64) {
                unsigned p = 0;
                float l = -3.4e38f;
                if (lane < c) {
                    p = sorted[b + lane];
                    l = lgt[b + lane];
                }
                float m = l;
#pragma unroll
                for (int off = 32; off > 0; off >>= 1) m = fmaxf(m, __shfl_xor(m, off));
                const float ex = (lane < c) ? __expf(l - m) : 0.f;
                float acc[8] = {0, 0, 0, 0, 0, 0, 0, 0};
                for (int i = 0; i < c; i += 8) {
                    unsigned p0 = __shfl(p, i + g);
                    unsigned p1 = __shfl(p, i + 4 + g);
                    float a0 = __shfl(ex, i + g);
                    float a1 = __shfl(ex, i + 4 + g);
                    uint4 v0 = *xwrow(xw, p0, ln);
                    uint4 v1 = *xwrow(xw, p1, ln);
                    accum8(acc, v0, a0);
                    accum8(acc, v1, a1);
                }
                float dsum = ex;
#pragma unroll
                for (int off = 32; off > 0; off >>= 1) dsum += __shfl_xor(dsum, off);
#pragma unroll
                for (int t = 0; t < 8; ++t) {
                    acc[t] += __shfl_xor(acc[t], 16);
                    acc[t] += __shfl_xor(acc[t], 32);
                }
                const float inv = 1.f / (dsum + 1e-16f);
#pragma unroll
                for (int j = 0; j < 2; ++j) {
                    const int t = g * 2 + j;
                    const int col = t * 16 + ln;
                    const float v = fmaxf(fmaf(acc[t], inv, bias[col]), 0.f);
                    if (outp) outp[(size_t)dd * F_DIM + col] = v;
                    if (hfp)  hfp[(size_t)dd * F_DIM + col] = (_Float16)v;
                }
            } else {
                // very-high-degree fallback: per-lane 2-col scalar path
                const int p0 = lane * 2;
                const int c0 = (p0 & 7) * 16 + (p0 >> 3);
                const int c1 = c0 + 16;
                float2 acc = make_float2(bias[c0], bias[c1]);
                float m = -3.4e38f;
                for (int i = b + lane; i < b + c; i += 64) m = fmaxf(m, lgt[i]);
#pragma unroll
                for (int off = 32; off > 0; off >>= 1) m = fmaxf(m, __shfl_xor(m, off));
                float dsum = 0.f;
                for (int i = b + lane; i < b + c; i += 64) dsum += __expf(lgt[i] - m);
#pragma unroll
                for (int off = 32; off > 0; off >>= 1) dsum += __shfl_xor(dsum, off);
                const float inv = 1.f / (dsum + 1e-16f);
                for (int i = b; i < b + c; ++i) {
                    unsigned pp = sorted[i];
                    float alpha = __expf(lgt[i] - m) * inv;
                    const __half2 h2 = *((const __half2*)xw + (((size_t)(pp >> 16)) * N_NODES + (pp & 0xffff)) * (F_DIM / 2) + lane);
                    float2 v = make_float2(__half2float(h2.x), __half2float(h2.y));
                    acc.x = fmaf(alpha, v.x, acc.x);
                    acc.y = fmaf(alpha, v.y, acc.y);
                }
                const float v0 = fmaxf(acc.x, 0.f), v1 = fmaxf(acc.y, 0.f);
                if (outp) { outp[(size_t)dd * F_DIM + c0] = v0; outp[(size_t)dd * F_DIM + c1] = v1; }
                if (hfp)  { hfp[(size_t)dd * F_DIM + c0] = (_Float16)v0; hfp[(size_t)dd * F_DIM + c1] = (_Float16)v1; }
            }
        }
    }
}

// ---------------- driver ----------------

extern "C" void kernel_launch(void* const* d_in, const int* in_sizes, int n_in,
                              void* d_out, int out_size, void* d_ws, size_t ws_size,
                              hipStream_t stream) {
    const float* x     = (const float*)d_in[0];
    const float* W     = (const float*)d_in[1];
    const float* att_q = (const float*)d_in[2];
    const float* att_k = (const float*)d_in[3];
    const float* bias  = (const float*)d_in[4];
    const int* ei      = (const int*)d_in[5];
    const int* etp     = (const int*)d_in[6];
    const int* srcp = ei;
    const int* dstp = ei + N_EDGES;
    float* out = (float*)d_out;
    char* ws   = (char*)d_ws;

    size_t off = 0;
    auto alloc = [&](size_t bytes) {
        void* p = ws + off;
        off = (off + bytes + 511) & ~(size_t)511;
        return p;
    };
    __half* xw       = (__half*)alloc((size_t)N_REL * N_NODES * F_DIM * sizeof(__half));
    float* a_q       = (float*)alloc((size_t)N_REL * N_NODES * sizeof(float));
    float* a_k       = (float*)alloc((size_t)N_REL * N_NODES * sizeof(float));
    int* cnt         = (int*)alloc((size_t)2 * N_NODES * sizeof(int));  // cnt + cursor, one memset
    int* cursor      = cnt + N_NODES;
    int* row_ptr     = (int*)alloc(((size_t)N_NODES + 1) * sizeof(int));
    int* partial     = (int*)alloc(256 * sizeof(int));
    unsigned* sorted = (unsigned*)alloc((size_t)N_EDGES * sizeof(unsigned));
    unsigned short* dst16 = (unsigned short*)alloc((size_t)N_EDGES * sizeof(unsigned short));
    float* lgt       = (float*)alloc((size_t)N_EDGES * sizeof(float));
    _Float16* Wf     = (_Float16*)alloc((size_t)N_LAYERS * N_REL * F_DIM * F_DIM * sizeof(_Float16));
    _Float16* Hf     = (_Float16*)alloc((size_t)N_NODES * F_DIM * sizeof(_Float16));

    prep_w<<<N_LAYERS * N_REL, 256, 0, stream>>>(W, Wf);
    hipMemsetAsync(cnt, 0, (size_t)2 * N_NODES * 4, stream);
    count_kernel<<<(N_EDGES + 255) / 256, 256, 0, stream>>>(dstp, cnt);
    block_sum_kernel<<<NBLK_N, 256, 0, stream>>>(cnt, partial);
    scan_partials_kernel<<<1, 256, 0, stream>>>(partial, row_ptr);
    scan_block_kernel<<<NBLK_N, 256, 0, stream>>>(cnt, partial, row_ptr);
    scatter_kernel<<<(N_EDGES + 255) / 256, 256, 0, stream>>>(
        srcp, dstp, etp, row_ptr, cursor, sorted, dst16);

    const int grid_h = (N_NODES * F_DIM / 8 + 255) / 256;   // 3125
    const int grid_m = (N_NODES + GBM - 1) / GBM;           // 196
    const int grid_e = (N_EDGES + 255) / 256;               // 1954
    prep_h<<<grid_h, 256, 0, stream>>>(x, Hf);              // layer-0 input only
    for (int l = 0; l < N_LAYERS; ++l) {
        gemm_xw<<<dim3(grid_m, N_REL), 256, 0, stream>>>(
            Hf, Wf + (size_t)l * N_REL * F_DIM * F_DIM,
            att_q + l * F_DIM, att_k + l * F_DIM,
            xw, a_q, a_k);
        logits_kernel<<<grid_e, 256, 0, stream>>>(a_q, a_k, sorted, dst16, lgt);
        const bool last = (l == N_LAYERS - 1);
        agg_fused<<<(N_NODES + 7) / 8, 256, 0, stream>>>(
            xw, lgt, row_ptr, sorted, bias + l * F_DIM,
            last ? out : nullptr,
            last ? nullptr : Hf);
    }
}